// Round 5
// baseline (530.542 us; speedup 1.0000x reference)
//
#include <hip/hip_runtime.h>
#include <hip/hip_bf16.h>
#include <cstdint>
#include <cstddef>

// Problem constants
#define HW   512
#define HW2  1024
#define SZ   (512 * 512)
#define NPT  (34 * 34)   // 1156 warped 1024-res points per 16x16 output tile
#define K_PTS 5          // ceil(1156 / 256)
#define WIN   44         // staged source window (512-res) per warp tile
#define WS    45         // padded LDS stride for the window
#define MARG  13         // window margin: covers |displacement| <= ~12 px

// jax.image.resize bilinear upsample 512->1024 taps for output index i (0..1023)
struct UpTap { int i0, i1; float w0, w1; };

__device__ __forceinline__ UpTap up_tap(int i) {
  UpTap t;
  int k = i >> 1;
  if ((i & 1) == 0) {
    t.i0 = k - 1; t.i1 = k; t.w0 = 0.25f; t.w1 = 0.75f;
    if (k == 0) { t.i0 = 0; t.w0 = 0.0f; t.w1 = 1.0f; }
  } else {
    t.i0 = k; t.i1 = k + 1; t.w0 = 0.75f; t.w1 = 0.25f;
    if (k == HW - 1) { t.i1 = HW - 1; t.w0 = 1.0f; t.w1 = 0.0f; }
  }
  return t;
}

// Value of bilinear-upsampled (512->1024) plane at integer 1024-coords, in-range assumed.
__device__ __forceinline__ float up_at(const float* __restrict__ plane, int yi, int xi) {
  UpTap ty = up_tap(yi), tx = up_tap(xi);
  const float* r0 = plane + (size_t)ty.i0 * HW;
  const float* r1 = plane + (size_t)ty.i1 * HW;
  float v00 = r0[tx.i0], v01 = r0[tx.i1];
  float v10 = r1[tx.i0], v11 = r1[tx.i1];
  return ty.w0 * (tx.w0 * v00 + tx.w1 * v01) + ty.w1 * (tx.w0 * v10 + tx.w1 * v11);
}

// Separable decomposition of (warp-bilinear in 1024-space) o (2x upsample):
// a 3-tap stencil on the 512 grid. Base clamped to [0,509]; out-of-range
// corners get weight 0 (zero padding, mask pre-clamp).
__device__ __forceinline__ void axis_taps(float s, int& base, float& w0, float& w1, float& w2) {
  float f0 = floorf(s);
  int i0 = (int)f0;
  float fr = s - f0;
  int b = (i0 & 1) ? (i0 >> 1) : (i0 >> 1) - 1;
  b = b < 0 ? 0 : (b > (HW - 3) ? (HW - 3) : b);
  float w[3] = {0.0f, 0.0f, 0.0f};
  if ((unsigned)i0 < (unsigned)HW2) {
    UpTap t = up_tap(i0);
    w[t.i0 - b] += (1.0f - fr) * t.w0;
    w[t.i1 - b] += (1.0f - fr) * t.w1;
  }
  if ((unsigned)(i0 + 1) < (unsigned)HW2) {
    UpTap t = up_tap(i0 + 1);
    w[t.i0 - b] += fr * t.w0;
    w[t.i1 - b] += fr * t.w1;
  }
  base = b; w0 = w[0]; w1 = w[1]; w2 = w[2];
}

// -------------------- K0: copy src channels (0..15) straight to output --------------------
__global__ void copy_src_kernel(const float* __restrict__ x, float* __restrict__ out) {
  const size_t half = (size_t)16 * SZ;
  const size_t nvec = half / 4;                 // float4
  size_t i = (size_t)blockIdx.x * blockDim.x + threadIdx.x;
  if (i < 2 * nvec) {
    size_t b = i / nvec, j = i % nvec;
    const float4* s = (const float4*)(x + b * 2 * half);
    float4* d = (float4*)(out + b * 2 * half);
    d[j] = s[j];
  }
}

// Per-point taps: window-relative (iy,ix) packed in pk (int16 pair), 6 weights.
struct PtTaps {
  int   pk;                        // (iy<<16) | (ix & 0xffff), window-relative
  float wy0, wy1, wy2, wx0, wx1, wx2;
};

__device__ __forceinline__ void compute_taps(const float* __restrict__ fx,
                                             const float* __restrict__ fy,
                                             int gx0, int gy0, int cx0, int ry0,
                                             int tid, PtTaps (&pt)[K_PTS]) {
  #pragma unroll
  for (int i = 0; i < K_PTS; ++i) {
    int p = tid + i * 256;
    pt[i].pk = 0;
    pt[i].wy0 = pt[i].wy1 = pt[i].wy2 = 0.0f;
    pt[i].wx0 = pt[i].wx1 = pt[i].wx2 = 0.0f;
    if (p < NPT) {
      int ry = p / 34, rx = p % 34;
      int yy = gy0 + ry, xx = gx0 + rx;
      if ((unsigned)yy < (unsigned)HW2 && (unsigned)xx < (unsigned)HW2) {
        float sx = (float)xx + 2.0f * up_at(fx, yy, xx);
        float sy = (float)yy + 2.0f * up_at(fy, yy, xx);
        int bx, by;
        axis_taps(sx, bx, pt[i].wx0, pt[i].wx1, pt[i].wx2);
        axis_taps(sy, by, pt[i].wy0, pt[i].wy1, pt[i].wy2);
        pt[i].pk = ((by - ry0) << 16) | ((bx - cx0) & 0xffff);
      }
    }
  }
}

// Evaluate one point for one channel: LDS window fast path, global fallback.
__device__ __forceinline__ float eval_pt(const float* __restrict__ s_win,
                                         const float* __restrict__ plane,
                                         int cx0, int ry0, const PtTaps& t) {
  int iy = t.pk >> 16;
  int ix = (int)(short)(t.pk & 0xffff);
  float r0, r1, r2;
  if ((unsigned)iy <= (unsigned)(WIN - 3) && (unsigned)ix <= (unsigned)(WIN - 3)) {
    const float* p = s_win + iy * WS + ix;
    r0 = t.wx0 * p[0]      + t.wx1 * p[1]          + t.wx2 * p[2];
    r1 = t.wx0 * p[WS]     + t.wx1 * p[WS + 1]     + t.wx2 * p[WS + 2];
    r2 = t.wx0 * p[2 * WS] + t.wx1 * p[2 * WS + 1] + t.wx2 * p[2 * WS + 2];
  } else {  // rare: displacement exceeded window margin
    const float* p = plane + (size_t)(ry0 + iy) * HW + (cx0 + ix);
    r0 = t.wx0 * p[0]      + t.wx1 * p[1]          + t.wx2 * p[2];
    r1 = t.wx0 * p[HW]     + t.wx1 * p[HW + 1]     + t.wx2 * p[HW + 2];
    r2 = t.wx0 * p[2 * HW] + t.wx1 * p[2 * HW + 1] + t.wx2 * p[2 * HW + 2];
  }
  return t.wy0 * r0 + t.wy1 * r1 + t.wy2 * r2;
}

// -------------------- K1/K4: res_warp_img(tgt, res_field, rollback=1) --------------------
// Per block: 16x16 output tile; LDS-staged 44x44 source window per channel.
__global__ void warp_img_kernel(const float* __restrict__ x,    // [B,32,512,512]
                                const float* __restrict__ res,  // [B,2,512,512]
                                float* __restrict__ out)        // [B,32,512,512]
{
  __shared__ float s_win[WIN * WS];
  __shared__ float s_tile[NPT];

  const int b = blockIdx.z;
  const int tx0 = blockIdx.x * 16, ty0 = blockIdx.y * 16;
  const int gx0 = tx0 * 2 - 1, gy0 = ty0 * 2 - 1;
  const int tid = threadIdx.x;

  // Window origin (clamped so the staged region is always fully in-bounds)
  int cx0 = tx0 - MARG; cx0 = cx0 < 0 ? 0 : (cx0 > HW - WIN ? HW - WIN : cx0);
  int ry0 = ty0 - MARG; ry0 = ry0 < 0 ? 0 : (ry0 > HW - WIN ? HW - WIN : ry0);

  const float* resx = res + (size_t)b * 2 * SZ;
  const float* resy = resx + SZ;

  // Phase 1: per-point separable 3x3 taps in registers (channel-independent)
  PtTaps pt[K_PTS];
  compute_taps(resx, resy, gx0, gy0, cx0, ry0, tid, pt);

  // Downsample stencil weights for this thread's output pixel
  const int ly = tid >> 4, lx = tid & 15;
  const int oy = ty0 + ly, ox = tx0 + lx;
  const float RW[4] = {0.25f, 0.75f, 0.75f, 0.25f};
  float wy[4], wx[4];
  float sumy = 0.f, sumx = 0.f;
  #pragma unroll
  for (int d = 0; d < 4; ++d) {
    int g = 2 * oy - 1 + d;
    wy[d] = ((unsigned)g < (unsigned)HW2) ? RW[d] : 0.0f; sumy += wy[d];
    g = 2 * ox - 1 + d;
    wx[d] = ((unsigned)g < (unsigned)HW2) ? RW[d] : 0.0f; sumx += wx[d];
  }
  const float inv = 1.0f / (sumy * sumx);

  for (int c = 0; c < 16; ++c) {
    const float* plane = x + ((size_t)b * 32 + 16 + c) * SZ;  // tgt channel c
    // Stage the 44x44 window (coalesced; always in-bounds)
    for (int i = tid; i < WIN * WIN; i += 256) {
      int r = i / WIN, cc = i % WIN;
      s_win[r * WS + cc] = plane[(size_t)(ry0 + r) * HW + (cx0 + cc)];
    }
    __syncthreads();
    // Gather warped values from LDS into s_tile
    #pragma unroll
    for (int i = 0; i < K_PTS; ++i) {
      int p = tid + i * 256;
      if (p < NPT) s_tile[p] = eval_pt(s_win, plane, cx0, ry0, pt[i]);
    }
    __syncthreads();
    // Antialiased 4x4 downsample
    float acc = 0.0f;
    #pragma unroll
    for (int dy = 0; dy < 4; ++dy) {
      float rowacc = 0.0f;
      const float* row = &s_tile[(2 * ly + dy) * 34 + 2 * lx];
      #pragma unroll
      for (int dx = 0; dx < 4; ++dx) rowacc += wx[dx] * row[dx];
      acc += wy[dy] * rowacc;
    }
    acc *= inv;
    out[(((size_t)b * 32 + 16 + c) * HW + oy) * HW + ox] = acc;
  }
}

// -------------------- K2: 3x3 conv over 50-ch bundle -> 2-ch adj --------------------
// 32x32 output tile per block; 34x34 halo staged in LDS per channel; 4 px/thread.
#define CTS 37   // conv LDS stride (34+3, odd-ish -> max 2-way bank aliasing)
__global__ void conv_kernel(const float* __restrict__ x,
                            const float* __restrict__ warped,  // = out, ch 16..31
                            const float* __restrict__ res,
                            const float* __restrict__ Wc,      // [2,50,3,3]
                            const float* __restrict__ bc,      // [2]
                            float* __restrict__ adj)           // [B,2,512,512]
{
  __shared__ float sw[900];
  __shared__ float s_ch[34 * CTS];
  const int tid = threadIdx.x;
  for (int i = tid; i < 900; i += 256) sw[i] = Wc[i];

  const int b = blockIdx.z;
  const int oy0 = blockIdx.y * 32, ox0 = blockIdx.x * 32;
  const int lr = tid >> 3;            // 0..31 output row in tile
  const int lc = (tid & 7) * 4;       // 0..28 first of 4 output cols

  float a0[4] = {0, 0, 0, 0}, a1[4] = {0, 0, 0, 0};

  for (int ic = 0; ic < 50; ++ic) {
    const float* plane;
    if (ic < 32)      plane = x      + ((size_t)b * 32 + ic) * SZ;
    else if (ic < 48) plane = warped + ((size_t)b * 32 + 16 + (ic - 32)) * SZ;
    else              plane = res    + ((size_t)b * 2 + (ic - 48)) * SZ;
    __syncthreads();   // previous iteration's reads done before overwrite
    for (int i = tid; i < 34 * 34; i += 256) {
      int r = i / 34, c = i % 34;
      int gy = oy0 - 1 + r, gx = ox0 - 1 + c;
      float v = 0.0f;
      if ((unsigned)gy < (unsigned)HW && (unsigned)gx < (unsigned)HW)
        v = plane[(size_t)gy * HW + gx];
      s_ch[r * CTS + c] = v;
    }
    __syncthreads();
    const float* w0 = &sw[ic * 9];
    const float* w1 = &sw[450 + ic * 9];
    float win[3][6];
    #pragma unroll
    for (int ky = 0; ky < 3; ++ky) {
      const float* rowp = &s_ch[(lr + ky) * CTS + lc];
      #pragma unroll
      for (int j = 0; j < 6; ++j) win[ky][j] = rowp[j];
    }
    #pragma unroll
    for (int j = 0; j < 4; ++j) {
      #pragma unroll
      for (int ky = 0; ky < 3; ++ky) {
        #pragma unroll
        for (int kx = 0; kx < 3; ++kx) {
          float v = win[ky][j + kx];
          a0[j] += v * w0[ky * 3 + kx];
          a1[j] += v * w1[ky * 3 + kx];
        }
      }
    }
  }
  const float b0 = bc[0], b1 = bc[1];
  const int oy = oy0 + lr, ox = ox0 + lc;
  float4 o0 = make_float4(a0[0] + b0, a0[1] + b0, a0[2] + b0, a0[3] + b0);
  float4 o1 = make_float4(a1[0] + b1, a1[1] + b1, a1[2] + b1, a1[3] + b1);
  *(float4*)&adj[((size_t)b * 2 + 0) * SZ + (size_t)oy * HW + ox] = o0;
  *(float4*)&adj[((size_t)b * 2 + 1) * SZ + (size_t)oy * HW + ox] = o1;
}

// -------------------- K3: new_res = adj + downsample(warp(up(res), 2*up(adj))) --------------------
// (the reference's *2 on the warped field values and the *0.5 after downsample cancel exactly)
__global__ void new_res_kernel(const float* __restrict__ res,  // [B,2,512,512]
                               const float* __restrict__ adj,  // [B,2,512,512]
                               float* __restrict__ nres)       // [B,2,512,512]
{
  __shared__ float s_win[WIN * WS];
  __shared__ float s_tile[NPT];

  const int b = blockIdx.z;
  const int tx0 = blockIdx.x * 16, ty0 = blockIdx.y * 16;
  const int gx0 = tx0 * 2 - 1, gy0 = ty0 * 2 - 1;
  const int tid = threadIdx.x;

  int cx0 = tx0 - MARG; cx0 = cx0 < 0 ? 0 : (cx0 > HW - WIN ? HW - WIN : cx0);
  int ry0 = ty0 - MARG; ry0 = ry0 < 0 ? 0 : (ry0 > HW - WIN ? HW - WIN : ry0);

  const float* adjx = adj + (size_t)b * 2 * SZ;
  const float* adjy = adjx + SZ;

  PtTaps pt[K_PTS];
  compute_taps(adjx, adjy, gx0, gy0, cx0, ry0, tid, pt);

  const int ly = tid >> 4, lx = tid & 15;
  const int oy = ty0 + ly, ox = tx0 + lx;
  const float RW[4] = {0.25f, 0.75f, 0.75f, 0.25f};
  float wy[4], wx[4];
  float sumy = 0.f, sumx = 0.f;
  #pragma unroll
  for (int d = 0; d < 4; ++d) {
    int g = 2 * oy - 1 + d;
    wy[d] = ((unsigned)g < (unsigned)HW2) ? RW[d] : 0.0f; sumy += wy[d];
    g = 2 * ox - 1 + d;
    wx[d] = ((unsigned)g < (unsigned)HW2) ? RW[d] : 0.0f; sumx += wx[d];
  }
  const float inv = 1.0f / (sumy * sumx);

  for (int c = 0; c < 2; ++c) {
    const float* plane = res + ((size_t)b * 2 + c) * SZ;
    for (int i = tid; i < WIN * WIN; i += 256) {
      int r = i / WIN, cc = i % WIN;
      s_win[r * WS + cc] = plane[(size_t)(ry0 + r) * HW + (cx0 + cc)];
    }
    __syncthreads();
    #pragma unroll
    for (int i = 0; i < K_PTS; ++i) {
      int p = tid + i * 256;
      if (p < NPT) s_tile[p] = eval_pt(s_win, plane, cx0, ry0, pt[i]);  // (x2, x0.5 folded)
    }
    __syncthreads();
    float acc = 0.0f;
    #pragma unroll
    for (int dy = 0; dy < 4; ++dy) {
      float rowacc = 0.0f;
      const float* row = &s_tile[(2 * ly + dy) * 34 + 2 * lx];
      #pragma unroll
      for (int dx = 0; dx < 4; ++dx) rowacc += wx[dx] * row[dx];
      acc += wy[dy] * rowacc;
    }
    acc = acc * inv + adjx[((size_t)c) * SZ + (size_t)oy * HW + ox];
    nres[((size_t)b * 2 + c) * SZ + (size_t)oy * HW + ox] = acc;
    __syncthreads();
  }
}

extern "C" void kernel_launch(void* const* d_in, const int* in_sizes, int n_in,
                              void* d_out, int out_size, void* d_ws, size_t ws_size,
                              hipStream_t stream) {
  const float* x   = (const float*)d_in[0];  // [2,32,512,512] f32
  const float* res = (const float*)d_in[1];  // [2,2,512,512]  f32
  const float* Wc  = (const float*)d_in[2];  // [2,50,3,3]     f32
  const float* bc  = (const float*)d_in[3];  // [2]            f32
  float* out = (float*)d_out;                // [2,32,512,512] f32

  float* adj  = (float*)d_ws;                // [2,2,512,512]
  float* nres = adj + (size_t)2 * 2 * SZ;    // [2,2,512,512]

  // K0: src passthrough (out channels 0..15 per batch)
  {
    const size_t nvec = 2 * ((size_t)16 * SZ / 4);
    copy_src_kernel<<<dim3((unsigned)((nvec + 255) / 256)), dim3(256), 0, stream>>>(x, out);
  }

  dim3 tile_grid(32, 32, 2);

  // K1: warped_tgt (stage A) -> out channels 16..31 (fp32 staging for conv)
  warp_img_kernel<<<tile_grid, dim3(256), 0, stream>>>(x, res, out);

  // K2: conv3x3 over [x(0..31) | out(16..31) | res] -> adj (32x32 tiles)
  conv_kernel<<<dim3(16, 16, 2), dim3(256), 0, stream>>>(x, out, res, Wc, bc, adj);

  // K3: new_res
  new_res_kernel<<<tile_grid, dim3(256), 0, stream>>>(res, adj, nres);

  // K4: hindsight warp -> out channels 16..31 (overwrites staging)
  warp_img_kernel<<<tile_grid, dim3(256), 0, stream>>>(x, nres, out);
}

// Round 6
// 418.399 us; speedup vs baseline: 1.2680x; 1.2680x over previous
//
#include <hip/hip_runtime.h>
#include <hip/hip_bf16.h>
#include <cstdint>
#include <cstddef>

// Problem constants
#define HW   512
#define HW2  1024
#define SZ   (512 * 512)
#define NPT  (34 * 34)   // 1156 warped 1024-res points per 16x16 output tile
#define K_PTS 5          // ceil(1156 / 256)

// jax.image.resize bilinear upsample 512->1024 taps for output index i (0..1023)
struct UpTap { int i0, i1; float w0, w1; };

__device__ __forceinline__ UpTap up_tap(int i) {
  UpTap t;
  int k = i >> 1;
  if ((i & 1) == 0) {
    t.i0 = k - 1; t.i1 = k; t.w0 = 0.25f; t.w1 = 0.75f;
    if (k == 0) { t.i0 = 0; t.w0 = 0.0f; t.w1 = 1.0f; }
  } else {
    t.i0 = k; t.i1 = k + 1; t.w0 = 0.75f; t.w1 = 0.25f;
    if (k == HW - 1) { t.i1 = HW - 1; t.w0 = 1.0f; t.w1 = 0.0f; }
  }
  return t;
}

// Value of bilinear-upsampled (512->1024) plane at integer 1024-coords (yi, xi), in-range assumed.
__device__ __forceinline__ float up_at(const float* __restrict__ plane, int yi, int xi) {
  UpTap ty = up_tap(yi), tx = up_tap(xi);
  const float* r0 = plane + (size_t)ty.i0 * HW;
  const float* r1 = plane + (size_t)ty.i1 * HW;
  float v00 = r0[tx.i0], v01 = r0[tx.i1];
  float v10 = r1[tx.i0], v11 = r1[tx.i1];
  return ty.w0 * (tx.w0 * v00 + tx.w1 * v01) + ty.w1 * (tx.w0 * v10 + tx.w1 * v11);
}

// Separable decomposition of (warp-bilinear in 1024-space) o (2x upsample):
// a 3-tap stencil on the 512 grid. Base clamped to [0,509]; out-of-range
// corners get weight 0 (zero padding, mask pre-clamp).
__device__ __forceinline__ void axis_taps(float s, int& base, float& w0, float& w1, float& w2) {
  float f0 = floorf(s);
  int i0 = (int)f0;
  float fr = s - f0;
  int b = (i0 & 1) ? (i0 >> 1) : (i0 >> 1) - 1;
  b = b < 0 ? 0 : (b > (HW - 3) ? (HW - 3) : b);
  float w[3] = {0.0f, 0.0f, 0.0f};
  if ((unsigned)i0 < (unsigned)HW2) {
    UpTap t = up_tap(i0);
    w[t.i0 - b] += (1.0f - fr) * t.w0;
    w[t.i1 - b] += (1.0f - fr) * t.w1;
  }
  if ((unsigned)(i0 + 1) < (unsigned)HW2) {
    UpTap t = up_tap(i0 + 1);
    w[t.i0 - b] += fr * t.w0;
    w[t.i1 - b] += fr * t.w1;
  }
  base = b; w0 = w[0]; w1 = w[1]; w2 = w[2];
}

// -------------------- K0: copy src channels (0..15) straight to output --------------------
__global__ void copy_src_kernel(const float* __restrict__ x, float* __restrict__ out) {
  const size_t half = (size_t)16 * SZ;
  const size_t nvec = half / 4;                 // float4
  size_t i = (size_t)blockIdx.x * blockDim.x + threadIdx.x;
  if (i < 2 * nvec) {
    size_t b = i / nvec, j = i % nvec;
    const float4* s = (const float4*)(x + b * 2 * half);
    float4* d = (float4*)(out + b * 2 * half);
    d[j] = s[j];
  }
}

// Per-point separable 3x3 stencil: global offset + 6 weights, in registers.
struct PtTaps {
  int   off;                       // by*HW + bx into the 512-plane
  float wy0, wy1, wy2, wx0, wx1, wx2;
};

__device__ __forceinline__ void compute_taps(const float* __restrict__ fx,
                                             const float* __restrict__ fy,
                                             int gx0, int gy0, int tid,
                                             PtTaps (&pt)[K_PTS]) {
  #pragma unroll
  for (int i = 0; i < K_PTS; ++i) {
    int p = tid + i * 256;
    pt[i].off = 0;
    pt[i].wy0 = pt[i].wy1 = pt[i].wy2 = 0.0f;
    pt[i].wx0 = pt[i].wx1 = pt[i].wx2 = 0.0f;
    if (p < NPT) {
      int ry = p / 34, rx = p % 34;
      int yy = gy0 + ry, xx = gx0 + rx;
      if ((unsigned)yy < (unsigned)HW2 && (unsigned)xx < (unsigned)HW2) {
        float sx = (float)xx + 2.0f * up_at(fx, yy, xx);
        float sy = (float)yy + 2.0f * up_at(fy, yy, xx);
        int bx, by;
        axis_taps(sx, bx, pt[i].wx0, pt[i].wx1, pt[i].wx2);
        axis_taps(sy, by, pt[i].wy0, pt[i].wy1, pt[i].wy2);
        pt[i].off = by * HW + bx;
      }
    }
  }
}

__device__ __forceinline__ float eval_taps(const float* __restrict__ plane, const PtTaps& t) {
  const float* p0 = plane + t.off;
  float r0 = t.wx0 * p0[0]        + t.wx1 * p0[1]          + t.wx2 * p0[2];
  float r1 = t.wx0 * p0[HW]       + t.wx1 * p0[HW + 1]     + t.wx2 * p0[HW + 2];
  float r2 = t.wx0 * p0[2 * HW]   + t.wx1 * p0[2 * HW + 1] + t.wx2 * p0[2 * HW + 2];
  return t.wy0 * r0 + t.wy1 * r1 + t.wy2 * r2;
}

// -------------------- K1/K4: res_warp_img(tgt, res_field, rollback=1) --------------------
// Per block: 16x16 output tile; 2 channels per barrier round (ILP + fewer barriers).
__global__ void warp_img_kernel(const float* __restrict__ x,    // [B,32,512,512]
                                const float* __restrict__ res,  // [B,2,512,512]
                                float* __restrict__ out)        // [B,32,512,512]
{
  __shared__ float s_tile0[NPT];
  __shared__ float s_tile1[NPT];

  const int b = blockIdx.z;
  const int tx0 = blockIdx.x * 16, ty0 = blockIdx.y * 16;
  const int gx0 = tx0 * 2 - 1, gy0 = ty0 * 2 - 1;
  const int tid = threadIdx.x;

  const float* resx = res + (size_t)b * 2 * SZ;
  const float* resy = resx + SZ;

  // Phase 1: per-point separable 3x3 taps in registers (channel-independent)
  PtTaps pt[K_PTS];
  compute_taps(resx, resy, gx0, gy0, tid, pt);

  // Downsample stencil weights for this thread's output pixel
  const int ly = tid >> 4, lx = tid & 15;
  const int oy = ty0 + ly, ox = tx0 + lx;
  const float RW[4] = {0.25f, 0.75f, 0.75f, 0.25f};
  float wy[4], wx[4];
  float sumy = 0.f, sumx = 0.f;
  #pragma unroll
  for (int d = 0; d < 4; ++d) {
    int g = 2 * oy - 1 + d;
    wy[d] = ((unsigned)g < (unsigned)HW2) ? RW[d] : 0.0f; sumy += wy[d];
    g = 2 * ox - 1 + d;
    wx[d] = ((unsigned)g < (unsigned)HW2) ? RW[d] : 0.0f; sumx += wx[d];
  }
  const float inv = 1.0f / (sumy * sumx);

  for (int c = 0; c < 16; c += 2) {
    const float* plane0 = x + ((size_t)b * 32 + 16 + c) * SZ;
    const float* plane1 = plane0 + SZ;
    // Phase 2: two channels' warped values into LDS (90 independent loads/thread)
    #pragma unroll
    for (int i = 0; i < K_PTS; ++i) {
      int p = tid + i * 256;
      if (p < NPT) {
        s_tile0[p] = eval_taps(plane0, pt[i]);
        s_tile1[p] = eval_taps(plane1, pt[i]);
      }
    }
    __syncthreads();
    // Phase 3: antialiased 4x4 downsample, both channels
    float acc0 = 0.0f, acc1 = 0.0f;
    #pragma unroll
    for (int dy = 0; dy < 4; ++dy) {
      float r0 = 0.0f, r1 = 0.0f;
      const int base = (2 * ly + dy) * 34 + 2 * lx;
      #pragma unroll
      for (int dx = 0; dx < 4; ++dx) {
        r0 += wx[dx] * s_tile0[base + dx];
        r1 += wx[dx] * s_tile1[base + dx];
      }
      acc0 += wy[dy] * r0;
      acc1 += wy[dy] * r1;
    }
    size_t o = (((size_t)b * 32 + 16 + c) * HW + oy) * HW + ox;
    out[o] = acc0 * inv;
    out[o + SZ] = acc1 * inv;
    __syncthreads();
  }
}

// -------------------- K2: 3x3 conv over 50-ch bundle -> 2-ch adj --------------------
__global__ void conv_kernel(const float* __restrict__ x,
                            const float* __restrict__ warped,  // = out, ch 16..31
                            const float* __restrict__ res,
                            const float* __restrict__ Wc,      // [2,50,3,3]
                            const float* __restrict__ bc,      // [2]
                            float* __restrict__ adj)           // [B,2,512,512]
{
  __shared__ float sw[900];
  const int tid = threadIdx.y * 16 + threadIdx.x;
  for (int i = tid; i < 900; i += 256) sw[i] = Wc[i];
  __syncthreads();

  const int b = blockIdx.z;
  const int oy = blockIdx.y * 16 + threadIdx.y;
  const int ox = blockIdx.x * 16 + threadIdx.x;

  float acc0 = bc[0];
  float acc1 = bc[1];

  for (int ic = 0; ic < 50; ++ic) {
    const float* w0 = &sw[ic * 9];
    const float* w1 = &sw[450 + ic * 9];
    const float* plane;
    if (ic < 32)      plane = x      + ((size_t)b * 32 + ic) * SZ;
    else if (ic < 48) plane = warped + ((size_t)b * 32 + 16 + (ic - 32)) * SZ;
    else              plane = res    + ((size_t)b * 2 + (ic - 48)) * SZ;
    #pragma unroll
    for (int ky = 0; ky < 3; ++ky) {
      int yy = oy + ky - 1;
      bool yok = (unsigned)yy < (unsigned)HW;
      #pragma unroll
      for (int kx = 0; kx < 3; ++kx) {
        int xx = ox + kx - 1;
        float v = 0.0f;
        if (yok && (unsigned)xx < (unsigned)HW)
          v = plane[(size_t)yy * HW + xx];
        acc0 += v * w0[ky * 3 + kx];
        acc1 += v * w1[ky * 3 + kx];
      }
    }
  }
  adj[((size_t)b * 2 + 0) * SZ + (size_t)oy * HW + ox] = acc0;
  adj[((size_t)b * 2 + 1) * SZ + (size_t)oy * HW + ox] = acc1;
}

// -------------------- K3: new_res = adj + downsample(warp(up(res), 2*up(adj))) --------------------
// (the reference's *2 on the warped field values and the *0.5 after downsample cancel exactly)
__global__ void new_res_kernel(const float* __restrict__ res,  // [B,2,512,512]
                               const float* __restrict__ adj,  // [B,2,512,512]
                               float* __restrict__ nres)       // [B,2,512,512]
{
  __shared__ float s_tile0[NPT];
  __shared__ float s_tile1[NPT];

  const int b = blockIdx.z;
  const int tx0 = blockIdx.x * 16, ty0 = blockIdx.y * 16;
  const int gx0 = tx0 * 2 - 1, gy0 = ty0 * 2 - 1;
  const int tid = threadIdx.x;

  const float* adjx = adj + (size_t)b * 2 * SZ;
  const float* adjy = adjx + SZ;

  PtTaps pt[K_PTS];
  compute_taps(adjx, adjy, gx0, gy0, tid, pt);

  const int ly = tid >> 4, lx = tid & 15;
  const int oy = ty0 + ly, ox = tx0 + lx;
  const float RW[4] = {0.25f, 0.75f, 0.75f, 0.25f};
  float wy[4], wx[4];
  float sumy = 0.f, sumx = 0.f;
  #pragma unroll
  for (int d = 0; d < 4; ++d) {
    int g = 2 * oy - 1 + d;
    wy[d] = ((unsigned)g < (unsigned)HW2) ? RW[d] : 0.0f; sumy += wy[d];
    g = 2 * ox - 1 + d;
    wx[d] = ((unsigned)g < (unsigned)HW2) ? RW[d] : 0.0f; sumx += wx[d];
  }
  const float inv = 1.0f / (sumy * sumx);

  const float* plane0 = res + (size_t)b * 2 * SZ;
  const float* plane1 = plane0 + SZ;
  #pragma unroll
  for (int i = 0; i < K_PTS; ++i) {
    int p = tid + i * 256;
    if (p < NPT) {
      s_tile0[p] = eval_taps(plane0, pt[i]);   // (x2 and x0.5 folded out)
      s_tile1[p] = eval_taps(plane1, pt[i]);
    }
  }
  __syncthreads();
  float acc0 = 0.0f, acc1 = 0.0f;
  #pragma unroll
  for (int dy = 0; dy < 4; ++dy) {
    float r0 = 0.0f, r1 = 0.0f;
    const int base = (2 * ly + dy) * 34 + 2 * lx;
    #pragma unroll
    for (int dx = 0; dx < 4; ++dx) {
      r0 += wx[dx] * s_tile0[base + dx];
      r1 += wx[dx] * s_tile1[base + dx];
    }
    acc0 += wy[dy] * r0;
    acc1 += wy[dy] * r1;
  }
  size_t o = ((size_t)b * 2) * SZ + (size_t)oy * HW + ox;
  nres[o]      = acc0 * inv + adjx[(size_t)oy * HW + ox];
  nres[o + SZ] = acc1 * inv + adjy[(size_t)oy * HW + ox];
}

extern "C" void kernel_launch(void* const* d_in, const int* in_sizes, int n_in,
                              void* d_out, int out_size, void* d_ws, size_t ws_size,
                              hipStream_t stream) {
  const float* x   = (const float*)d_in[0];  // [2,32,512,512] f32
  const float* res = (const float*)d_in[1];  // [2,2,512,512]  f32
  const float* Wc  = (const float*)d_in[2];  // [2,50,3,3]     f32
  const float* bc  = (const float*)d_in[3];  // [2]            f32
  float* out = (float*)d_out;                // [2,32,512,512] f32

  float* adj  = (float*)d_ws;                // [2,2,512,512]
  float* nres = adj + (size_t)2 * 2 * SZ;    // [2,2,512,512]

  // K0: src passthrough (out channels 0..15 per batch)
  {
    const size_t nvec = 2 * ((size_t)16 * SZ / 4);
    copy_src_kernel<<<dim3((unsigned)((nvec + 255) / 256)), dim3(256), 0, stream>>>(x, out);
  }

  dim3 tile_grid(32, 32, 2);

  // K1: warped_tgt (stage A) -> out channels 16..31 (fp32 staging for conv)
  warp_img_kernel<<<tile_grid, dim3(256), 0, stream>>>(x, res, out);

  // K2: conv3x3 over [x(0..31) | out(16..31) | res] -> adj
  conv_kernel<<<tile_grid, dim3(16, 16), 0, stream>>>(x, out, res, Wc, bc, adj);

  // K3: new_res
  new_res_kernel<<<tile_grid, dim3(256), 0, stream>>>(res, adj, nres);

  // K4: hindsight warp -> out channels 16..31 (overwrites staging)
  warp_img_kernel<<<tile_grid, dim3(256), 0, stream>>>(x, nres, out);
}